// Round 9
// baseline (413.805 us; speedup 1.0000x reference)
//
#include <hip/hip_runtime.h>
#include <hip/hip_fp16.h>
#include <math.h>

#define T_LEN   2048
#define NB      256
#define N_FREQ  1024
#define DMODEL  64
#define HORIZON 720

// ws layout: u32[8..9] = barrier counters (zeroed by memset with amp);
// float[64..1088) = amp; Y0/Y1 conv outputs.
#define WS_BAR  8
#define WS_AMP  64
#define WS_Y0   2048
#define WS_Y1   (2048 + NB * T_LEN)

#define PMAX_FAST 191
#define CHUNK   1024
#define HSTRIDE 1412    // fp16 dk stride: HN_max (1024+2*191+2=1408) + zslot
#define ZSLOT   1408
#define XS2N    1796    // staged x window [t0-384, t0+1408) f16 + pad
#define ZXS     1795

// smem overlays (bytes):
//  fft:  buf0@0 (8192) buf1@8192 (8192) tw@16384 (4096)          -> 20480
//  conv: dk@0 (25416)  xs2@25424 (3592)                          -> 29016
//  fall: w1s@0 w2s@2304 b1s@4608 fxs@4864 hs@5488 (25856)        -> 31344
//  gemm: As@0 (4608) Bs@4608 (4608)                              -> 9216
#define SMEM_BYTES 31360

typedef _Float16 h4 __attribute__((ext_vector_type(4)));
typedef float    fx4 __attribute__((ext_vector_type(4)));

__device__ __forceinline__ float gelu_fast(float a) {
    float a2 = a * a;
    float z  = a * fmaf(-0.07135481627159498f, a2, -1.5957691216057308f);
    float e  = __expf(z);
    return a * __builtin_amdgcn_rcpf(1.0f + e);
}

__device__ __forceinline__ __half2 gelu2(float x, float y) {
    __half2 a  = __float22half2_rn(make_float2(x, y));
    __half2 a2 = __hmul2(a, a);
    const __half2 c2 = __float2half2_rn(-0.07135481627159498f);
    const __half2 c1 = __float2half2_rn(-1.5957691216057308f);
    __half2 z = __hmul2(a, __hfma2(c2, a2, c1));
    __half2 e = h2exp(z);
    const __half2 one = __float2half2_rn(1.0f);
    return __hmul2(a, h2rcp(__hadd2(one, e)));
}

__device__ __forceinline__ h4 gelu4(fx4 h) {
    union { __half2 p[2]; h4 v; } u;
    u.p[0] = gelu2(h[0], h[1]);
    u.p[1] = gelu2(h[2], h[3]);
    return u.v;
}

__device__ __forceinline__ float2 cmul(float2 a, float2 b) {
    return make_float2(a.x * b.x - a.y * b.y, a.x * b.y + a.y * b.x);
}

__device__ __forceinline__ unsigned magic_div(unsigned d) {
    return (unsigned)((0x100000000ULL + d - 1) / d);
}

// Device-scope grid barrier: release-fence, arrive, acquire-spin (bounded ->
// wrong-answer instead of hang on co-residency failure), acquire-fence.
// Co-residency guaranteed: 1024 blocks, launch_bounds(256,4) (VGPR<=128),
// LDS 31.4KB -> >=4 blocks/CU on 256 CUs.
__device__ __forceinline__ void grid_barrier(unsigned* ctr, int tid) {
    __syncthreads();
    __threadfence();                       // release: writeback dirty L2 (cross-XCD)
    if (tid == 0) {
        __hip_atomic_fetch_add(ctr, 1u, __ATOMIC_ACQ_REL, __HIP_MEMORY_SCOPE_AGENT);
        int spins = 0;
        while (__hip_atomic_load(ctr, __ATOMIC_ACQUIRE, __HIP_MEMORY_SCOPE_AGENT) < 1024u) {
            __builtin_amdgcn_s_sleep(8);
            if (++spins > (1 << 22)) break;   // hang-proof
        }
    }
    __syncthreads();
    __threadfence();                       // acquire: invalidate stale lines
}

// ---------------------------------------------------------------------------
// Inline top-2 of amp (4 KB) + period/weight derivation, per block.
// ---------------------------------------------------------------------------
__device__ __forceinline__ void compute_meta(const float* __restrict__ amp,
                                             float* sf, int* si, int tid,
                                             int& P1, int& cols1, int& P2, int& cols2,
                                             float& wg1, float& wg2) {
    float* v1s = sf;        float* v2s = sf + 256;
    int*   i1s = si;        int*   i2s = si + 256;
    float4 v4 = ((const float4*)amp)[tid];
    float vv[4] = {v4.x, v4.y, v4.z, v4.w};
    float v1 = -1e30f, v2 = -1e30f; int i1 = 1 << 30, i2 = 1 << 30;
    #pragma unroll
    for (int u = 0; u < 4; ++u) {
        int j = tid * 4 + u;
        float v = vv[u];
        if (v > v1) { v2 = v1; i2 = i1; v1 = v; i1 = j; }
        else if (v > v2) { v2 = v; i2 = j; }
    }
    v1s[tid] = v1; i1s[tid] = i1; v2s[tid] = v2; i2s[tid] = i2;
    __syncthreads();
    for (int st = 128; st > 0; st >>= 1) {
        if (tid < st) {
            float w1 = v1s[tid + st]; int j1 = i1s[tid + st];
            float w2 = v2s[tid + st]; int j2 = i2s[tid + st];
            float a1 = v1s[tid];      int a1i = i1s[tid];
            float a2 = v2s[tid];      int a2i = i2s[tid];
            float n1, n2; int n1i, n2i;
            bool w1_first = (w1 > a1) || (w1 == a1 && j1 < a1i);
            if (w1_first) {
                n1 = w1; n1i = j1;
                bool a1_next = (a1 > w2) || (a1 == w2 && a1i < j2);
                if (a1_next) { n2 = a1; n2i = a1i; } else { n2 = w2; n2i = j2; }
            } else {
                n1 = a1; n1i = a1i;
                bool w1_next = (w1 > a2) || (w1 == a2 && j1 < a2i);
                if (w1_next) { n2 = w1; n2i = j1; } else { n2 = a2; n2i = a2i; }
            }
            v1s[tid] = n1; i1s[tid] = n1i; v2s[tid] = n2; i2s[tid] = n2i;
        }
        __syncthreads();
    }
    float v1f = v1s[0], v2f = v2s[0];
    int f1 = i1s[0] + 1, f2 = i2s[0] + 1;
    __syncthreads();
    P1 = (int)llround(2048.0 / (double)f1); if (P1 < 1) P1 = 1;
    P2 = (int)llround(2048.0 / (double)f2); if (P2 < 1) P2 = 1;
    cols1 = (T_LEN + P1 - 1) / P1;
    cols2 = (T_LEN + P2 - 1) / P2;
    float mx = fmaxf(v1f, v2f);
    float e1 = __expf(v1f - mx), e2 = __expf(v2f - mx);
    float inv = 1.0f / (e1 + e2);
    wg1 = e1 * inv; wg2 = e2 * inv;
}

// ---------------------------------------------------------------------------
// ONE normal-launch kernel for the whole pipeline (no cooperative API; manual
// device-scope barriers). 1024 blocks x 256 threads, co-resident by
// construction. Phases (all bodies = R8's verified per-kernel code):
//   P0 zero out -> P1 FFT (blocks<256) -> BAR -> P2 conv (all) -> BAR ->
//   P3 head GEMM split-K x4 (blocks<736, atomicAdd + bias).
// Replaces 4 kernel dispatches (+their gaps) with 1.
// ---------------------------------------------------------------------------
__global__ __launch_bounds__(256, 4) void mega_kernel(
    const float* __restrict__ x,
    const float* __restrict__ w1, const float* __restrict__ b1,
    const float* __restrict__ w2, const float* __restrict__ b2,
    const float* __restrict__ hw, const float* __restrict__ hb,
    float* __restrict__ ws, float* __restrict__ out)
{
    __shared__ __align__(16) unsigned char smem[SMEM_BYTES];
    const int tid = threadIdx.x;
    const int bid = blockIdx.x;
    float* amp = ws + WS_AMP;
    unsigned* bar = (unsigned*)ws + WS_BAR;

    // ================= P0: zero out (1024 x 45 = 46080 float4 exactly) =====
    if (tid < 45) ((float4*)out)[bid * 45 + tid] = make_float4(0.f, 0.f, 0.f, 0.f);

    // ================= P1: FFT (blocks 0..255, one batch each) =============
    if (bid < NB) {
        float2* buf0 = (float2*)smem;
        float2* buf1 = (float2*)(smem + 8192);
        float2* tw   = (float2*)(smem + 16384);
        const int b = bid;
        {
            float s, c;
            __sincosf((float)tid * 6.135923151542565e-3f, &s, &c);          // 2*pi/1024
            tw[tid] = make_float2(c, -s);
            __sincosf((float)(tid + 256) * 6.135923151542565e-3f, &s, &c);
            tw[tid + 256] = make_float2(c, -s);
        }
        const float2* xz = (const float2*)(x + b * T_LEN);
        buf0[tid]       = xz[tid];
        buf0[tid + 256] = xz[tid + 256];
        buf0[tid + 512] = xz[tid + 512];
        buf0[tid + 768] = xz[tid + 768];
        __syncthreads();

        float2* src = buf0;
        float2* dst = buf1;
        for (int s = 0; s < 10; s += 2) {
            const int Ns = 1 << s;
            const int j1 = tid;
            const int q  = j1 & (Ns - 1);
            const int hi = j1 >> s;
            float2 A = src[j1];
            float2 B = src[j1 + 512];
            float2 C = src[j1 + 256];
            float2 D = src[j1 + 768];
            float2 w  = tw[q << (9 - s)];
            float2 wB = cmul(w, B);
            float2 wD = cmul(w, D);
            float2 P0v = make_float2(A.x + wB.x, A.y + wB.y);
            float2 P1v = make_float2(A.x - wB.x, A.y - wB.y);
            float2 Q0 = make_float2(C.x + wD.x, C.y + wD.y);
            float2 Q1 = make_float2(C.x - wD.x, C.y - wD.y);
            float2 wa = tw[q << (8 - s)];
            float2 wb = tw[(q + Ns) << (8 - s)];
            float2 t0 = cmul(wa, Q0);
            float2 t1 = cmul(wb, Q1);
            const int O = (hi << (s + 2)) + q;
            dst[O]          = make_float2(P0v.x + t0.x, P0v.y + t0.y);
            dst[O + 2 * Ns] = make_float2(P0v.x - t0.x, P0v.y - t0.y);
            dst[O + Ns]     = make_float2(P1v.x + t1.x, P1v.y + t1.y);
            dst[O + 3 * Ns] = make_float2(P1v.x - t1.x, P1v.y - t1.y);
            __syncthreads();
            float2* tmp = src; src = dst; dst = tmp;
        }
        const int rot = (b * 8) & 1023;
        #pragma unroll
        for (int j = 0; j < 4; ++j) {
            const int kk = (tid + j * 256 + rot) & 1023;
            const int k  = kk + 1;
            float mag;
            if (k == 1024) {
                float2 Z0 = src[0];
                mag = fabsf(Z0.x - Z0.y) * (1.0f / 256.0f);
            } else {
                float2 Zk = src[k];
                float2 Zn = src[1024 - k];
                float Ax = 0.5f * (Zk.x + Zn.x), Ay = 0.5f * (Zk.y - Zn.y);
                float Bx = 0.5f * (Zk.y + Zn.y), By = -0.5f * (Zk.x - Zn.x);
                float sn, cs;
                __sincosf((float)k * 3.0679615757712823e-3f, &sn, &cs);  // pi/1024
                float Xx = Ax + cs * Bx + sn * By;
                float Xy = Ay + cs * By - sn * Bx;
                mag = sqrtf(Xx * Xx + Xy * Xy) * (1.0f / 256.0f);
            }
            atomicAdd(amp + kk, mag);   // device-scope, coherent
        }
    }

    grid_barrier(&bar[0], tid);

    // ================= P2: conv (all 1024 blocks) ==========================
    {
        _Float16 (*dk)[HSTRIDE] = (_Float16 (*)[HSTRIDE])smem;
        _Float16* xs2 = (_Float16*)(smem + 25424);

        const int per = bid >> 9;
        const int u   = bid & 511;
        const int b   = u >> 1;
        const int ci  = u & 1;
        const int t0  = ci * CHUNK;
        const int bT  = b * T_LEN;

        // stage x window early (P-independent); latency hides under meta
        for (int j = tid; j < XS2N; j += 256) {
            const int t = t0 - 384 + j;
            xs2[j] = (_Float16)((j < 1792 && t >= 0 && t < T_LEN) ? x[bT + t] : 0.f);
        }

        int P1_, cols1, P2_, cols2; float wg1, wg2;
        compute_meta(amp, (float*)dk, (int*)dk + 512, tid, P1_, cols1, P2_, cols2, wg1, wg2);

        const int P    = per == 0 ? P1_ : P2_;
        const int cols = per == 0 ? cols1 : cols2;
        const float wgt = per == 0 ? wg1 : wg2;
        float* yout = ws + (per == 0 ? WS_Y0 : WS_Y1);

        if (P >= 2 && P <= PMAX_FAST) {
            // ---- fast path (R8-verified) ----
            const int U0  = t0 - (P + 1);
            const int HN  = CHUNK + 2 * P + 2;
            const unsigned MP = magic_div((unsigned)P);
            const int IB0 = 383 - P;

            const int lane = tid & 63;
            const int wv   = tid >> 6;
            const int lm   = lane & 15;
            const int lg   = lane >> 4;

            h4  w1f[4], w2f[4];
            fx4 b1f[4];
            #pragma unroll
            for (int t = 0; t < 4; ++t) {
                #pragma unroll
                for (int i = 0; i < 4; ++i) {
                    const int k = lg * 4 + i;
                    w1f[t][i] = (_Float16)((k < 9) ? w1[(t * 16 + lm) * 9 + k] : 0.f);
                    w2f[t][i] = (_Float16)((lm < 9) ? w2[(t * 16 + k) * 9 + lm] : 0.f);
                    b1f[t][i] = b1[t * 16 + k];
                }
            }

            const int HN16 = (HN + 15) >> 4;
            const fx4 zf4 = {0.f, 0.f, 0.f, 0.f};

            for (int nt = wv; nt < HN16; nt += 4) {
                const int ih = nt * 16 + lm;
                const int uu0 = U0 + ih;
                const int uu = uu0 < 0 ? 0 : uu0;
                const int cc = (int)__umulhi((unsigned)uu, MP);
                const int pp = uu - cc * P;
                const bool rm = pp > 0, rp = pp < P - 1, cm = cc > 0, cp = (cc + 1) < cols;
                const int ibase = ih + IB0;
                h4 xb;
                #pragma unroll
                for (int j = 0; j < 4; ++j) {
                    const int tap = lg * 4 + j;
                    const int q = (tap * 86) >> 8;
                    const int r = tap - q * 3;
                    const bool ok = (tap < 9)
                        && (q > 0 || rm) && (q < 2 || rp)
                        && (r > 0 || cm) && (r < 2 || cp);
                    const int addr = ok ? (ibase + (r - 1) * P + (q - 1)) : ZXS;
                    xb[j] = xs2[addr];
                }
                fx4 h0 = __builtin_amdgcn_mfma_f32_16x16x16f16(w1f[0], xb, b1f[0], 0, 0, 0);
                fx4 h1 = __builtin_amdgcn_mfma_f32_16x16x16f16(w1f[1], xb, b1f[1], 0, 0, 0);
                fx4 h2 = __builtin_amdgcn_mfma_f32_16x16x16f16(w1f[2], xb, b1f[2], 0, 0, 0);
                fx4 h3 = __builtin_amdgcn_mfma_f32_16x16x16f16(w1f[3], xb, b1f[3], 0, 0, 0);
                h4 g0 = gelu4(h0);
                h4 g1 = gelu4(h1);
                h4 g2 = gelu4(h2);
                h4 g3 = gelu4(h3);
                fx4 da = __builtin_amdgcn_mfma_f32_16x16x16f16(w2f[0], g0, zf4, 0, 0, 0);
                fx4 db = __builtin_amdgcn_mfma_f32_16x16x16f16(w2f[1], g1, zf4, 0, 0, 0);
                da = __builtin_amdgcn_mfma_f32_16x16x16f16(w2f[2], g2, da, 0, 0, 0);
                db = __builtin_amdgcn_mfma_f32_16x16x16f16(w2f[3], g3, db, 0, 0, 0);
                if (ih < HN) {
                    #pragma unroll
                    for (int i = 0; i < 4; ++i) {
                        const int row = lg * 4 + i;
                        if (row < 9) dk[row][ih] = (_Float16)(da[i] + db[i]);
                    }
                }
            }
            if (tid < 9) dk[tid][ZSLOT] = (_Float16)0.f;
            __syncthreads();

            const float bias2 = b2[0];
            #pragma unroll
            for (int o = 0; o < 4; ++o) {
                const int t = t0 + tid + o * 256;
                const int iout = tid + o * 256 + (P + 1);
                const int cc = (int)__umulhi((unsigned)t, MP);
                const int pp = t - cc * P;
                const bool rm = pp > 0, rp = pp < P - 1, cm = cc > 0, cp = (cc + 1) < cols;
                const int i0 = (rm && cm) ? iout - P - 1 : ZSLOT;
                const int i1 = rm         ? iout - 1     : ZSLOT;
                const int i2 = (rm && cp) ? iout + P - 1 : ZSLOT;
                const int i3 = cm         ? iout - P     : ZSLOT;
                const int i5 = cp         ? iout + P     : ZSLOT;
                const int i6 = (rp && cm) ? iout - P + 1 : ZSLOT;
                const int i7 = rp         ? iout + 1     : ZSLOT;
                const int i8 = (rp && cp) ? iout + P + 1 : ZSLOT;
                float s = (float)dk[4][iout];
                s += (float)dk[0][i0]; s += (float)dk[1][i1]; s += (float)dk[2][i2];
                s += (float)dk[3][i3]; s += (float)dk[5][i5]; s += (float)dk[6][i6];
                s += (float)dk[7][i7]; s += (float)dk[8][i8];
                yout[bT + t] = wgt * (s + bias2);
            }
        } else {
            // ---- fallback tile path (rare); VGPR capped by launch_bounds ----
            float* w1s = (float*)smem;                       // [576]
            float* w2s = w1s + 576;                          // [576]
            float* b1s = w2s + 576;                          // [64]
            float (*fxs)[13] = (float (*)[13])(b1s + 64);    // [12][13]
            float (*hs)[101] = (float (*)[101])(b1s + 64 + 156); // [64][101]

            for (int i = tid; i < DMODEL * 9; i += 256) { w1s[i] = w1[i]; w2s[i] = w2[i]; }
            if (tid < DMODEL) b1s[tid] = b1[tid];
            const float bias2 = b2[0];

            const int tp = (P + 7) >> 3;
            const int tc = (cols + 7) >> 3;
            const int tiles_img = tp * tc;
            const int total = tiles_img * NB;

            for (int tile = u; tile < total; tile += 512) {
                const int bb = tile / tiles_img;
                const int ti  = tile - bb * tiles_img;
                const int tpi = ti / tc;
                const int tci = ti - tpi * tc;
                const int p0 = tpi * 8, c0 = tci * 8;

                __syncthreads();
                if (tid < 144) {
                    int i = tid / 12, j = tid - (tid / 12) * 12;
                    int pp = p0 - 2 + i, cc = c0 - 2 + j;
                    float v = 0.f;
                    if (pp >= 0 && pp < P && cc >= 0 && cc < cols) {
                        int t = cc * P + pp;
                        if (t < T_LEN) v = x[bb * T_LEN + t];
                    }
                    fxs[i][j] = v;
                }
                __syncthreads();

                for (int it = 0; it < 25; ++it) {
                    int idx = it * 256 + tid;
                    int ch = idx / 100;
                    int px = idx - ch * 100;
                    int pi = px / 10;
                    int pj = px - pi * 10;
                    const float* w = &w1s[ch * 9];
                    float a = b1s[ch];
                    a = fmaf(w[0], fxs[pi    ][pj    ], a);
                    a = fmaf(w[1], fxs[pi    ][pj + 1], a);
                    a = fmaf(w[2], fxs[pi    ][pj + 2], a);
                    a = fmaf(w[3], fxs[pi + 1][pj    ], a);
                    a = fmaf(w[4], fxs[pi + 1][pj + 1], a);
                    a = fmaf(w[5], fxs[pi + 1][pj + 2], a);
                    a = fmaf(w[6], fxs[pi + 2][pj    ], a);
                    a = fmaf(w[7], fxs[pi + 2][pj + 1], a);
                    a = fmaf(w[8], fxs[pi + 2][pj + 2], a);
                    float g = gelu_fast(a);
                    int pp = p0 - 1 + pi, cc = c0 - 1 + pj;
                    bool in_img = (pp >= 0) & (pp < P) & (cc >= 0) & (cc < cols);
                    hs[ch][px] = in_img ? g : 0.0f;
                }
                __syncthreads();

                {
                    const int pixel = tid >> 2, part = tid & 3;
                    const int pi = pixel >> 3, pj = pixel & 7;
                    const int base = pi * 10 + pj;
                    float s = 0.f;
                    for (int ch = part * 16; ch < part * 16 + 16; ++ch) {
                        const float* w  = &w2s[ch * 9];
                        const float* hr = &hs[ch][base];
                        s = fmaf(w[0], hr[0],  s);
                        s = fmaf(w[1], hr[1],  s);
                        s = fmaf(w[2], hr[2],  s);
                        s = fmaf(w[3], hr[10], s);
                        s = fmaf(w[4], hr[11], s);
                        s = fmaf(w[5], hr[12], s);
                        s = fmaf(w[6], hr[20], s);
                        s = fmaf(w[7], hr[21], s);
                        s = fmaf(w[8], hr[22], s);
                    }
                    s += __shfl_down(s, 1);
                    s += __shfl_down(s, 2);
                    if (part == 0) {
                        int pp = p0 + pi, cc = c0 + pj;
                        if (pp < P && cc < cols) {
                            int t = cc * P + pp;
                            if (t < T_LEN) yout[bb * T_LEN + t] = wgt * (s + bias2);
                        }
                    }
                }
            }
        }
    }

    grid_barrier(&bar[1], tid);

    // ================= P3: head GEMM (blocks 0..735), split-K x4 ===========
    if (bid < 736) {
        _Float16 (*As)[72] = (_Float16 (*)[72])smem;
        _Float16 (*Bs)[72] = (_Float16 (*)[72])(smem + 4608);
        const float* y0 = ws + WS_Y0;
        const float* y1 = ws + WS_Y1;
        const int kz = bid & 3;
        const int tl = bid >> 2;           // 0..183
        const int b0 = (tl & 7) * 32;
        const int h0 = (tl >> 3) * 32;
        const int kc0 = kz * 512;
        const int lane = tid & 63;
        const int wv   = tid >> 6;
        const int lm   = lane & 15;
        const int lg   = lane >> 4;
        const int wm   = (wv & 1) * 16;
        const int wn   = (wv >> 1) * 16;
        const int sr = tid >> 4;
        const int sq = (tid & 15) * 4;

        fx4 acc = {0.f, 0.f, 0.f, 0.f};

        for (int k0 = kc0; k0 < kc0 + 512; k0 += 64) {
            #pragma unroll
            for (int hh = 0; hh < 2; ++hh) {
                const int r = sr + hh * 16;
                const int src = (b0 + r) * T_LEN + k0 + sq;
                float4 uu = *(const float4*)(y0 + src);
                float4 vv = *(const float4*)(y1 + src);
                As[r][sq + 0] = (_Float16)(uu.x + vv.x);
                As[r][sq + 1] = (_Float16)(uu.y + vv.y);
                As[r][sq + 2] = (_Float16)(uu.z + vv.z);
                As[r][sq + 3] = (_Float16)(uu.w + vv.w);
                const int hr = h0 + r;
                float4 w = (hr < HORIZON) ? *(const float4*)(hw + hr * T_LEN + k0 + sq)
                                          : make_float4(0.f, 0.f, 0.f, 0.f);
                Bs[r][sq + 0] = (_Float16)w.x;
                Bs[r][sq + 1] = (_Float16)w.y;
                Bs[r][sq + 2] = (_Float16)w.z;
                Bs[r][sq + 3] = (_Float16)w.w;
            }
            __syncthreads();
            #pragma unroll
            for (int kk = 0; kk < 64; kk += 16) {
                h4 af = *(const h4*)&As[wm + lm][kk + lg * 4];
                h4 bf = *(const h4*)&Bs[wn + lm][kk + lg * 4];
                acc = __builtin_amdgcn_mfma_f32_16x16x16f16(af, bf, acc, 0, 0, 0);
            }
            __syncthreads();
        }
        const int ncol = h0 + wn + lm;
        if (ncol < HORIZON) {
            const float bb = (kz == 0) ? hb[ncol] : 0.f;
            #pragma unroll
            for (int i = 0; i < 4; ++i) {
                const int m = b0 + wm + lg * 4 + i;
                atomicAdd(&out[m * HORIZON + ncol], acc[i] + bb);
            }
        }
    }
}

// ---------------------------------------------------------------------------
extern "C" void kernel_launch(void* const* d_in, const int* in_sizes, int n_in,
                              void* d_out, int out_size, void* d_ws, size_t ws_size,
                              hipStream_t stream) {
    const float* x   = (const float*)d_in[0];
    const float* c1w = (const float*)d_in[1];
    const float* c1b = (const float*)d_in[2];
    const float* c2w = (const float*)d_in[3];
    const float* c2b = (const float*)d_in[4];
    const float* hw  = (const float*)d_in[5];
    const float* hb  = (const float*)d_in[6];
    float* out = (float*)d_out;
    float* ws  = (float*)d_ws;

    // zero barrier counters + amp (bytes 0..4351 of ws) in one memset
    hipMemsetAsync(ws, 0, (64 + N_FREQ) * sizeof(float), stream);
    mega_kernel<<<1024, 256, 0, stream>>>(x, c1w, c1b, c2w, c2b, hw, hb, ws, out);
}

// Round 10
// 131.719 us; speedup vs baseline: 3.1416x; 3.1416x over previous
//
#include <hip/hip_runtime.h>
#include <hip/hip_fp16.h>
#include <math.h>

#define T_LEN   2048
#define NB      256
#define N_FREQ  1024
#define DMODEL  64
#define HORIZON 720

// ws layout in floats
#define WS_AMP  64                    // 1024 floats, memset to 0 each launch
#define WS_Y0   2048
#define WS_Y1   (2048 + NB * T_LEN)

#define PMAX_FAST 191
#define CHUNK   1024
#define HSTRIDE 1412    // fp16 dk stride: HN_max (1024+2*191+2=1408) + zslot
#define ZSLOT   1408
#define XS2N    1796    // staged x window [t0-384, t0+1408) f16 + pad
#define ZXS     1795

// conv_all smem overlays (bytes):
//  fast: dk@0 (25416)  xs2@25424 (3592)                      -> 29016
//  fall: w1s@0 w2s@2304 b1s@4608 fxs@4864 hs@5488 (25856)    -> 31344
#define SMEM_BYTES 31360

typedef _Float16 h4 __attribute__((ext_vector_type(4)));
typedef float    fx4 __attribute__((ext_vector_type(4)));

// cheap tanh-GELU (f32, fallback path)
__device__ __forceinline__ float gelu_fast(float a) {
    float a2 = a * a;
    float z  = a * fmaf(-0.07135481627159498f, a2, -1.5957691216057308f);
    float e  = __expf(z);
    return a * __builtin_amdgcn_rcpf(1.0f + e);
}

// packed-f16 GELU; output half2 == 2 f16 B-frag elems (fast path)
__device__ __forceinline__ __half2 gelu2(float x, float y) {
    __half2 a  = __float22half2_rn(make_float2(x, y));
    __half2 a2 = __hmul2(a, a);
    const __half2 c2 = __float2half2_rn(-0.07135481627159498f);
    const __half2 c1 = __float2half2_rn(-1.5957691216057308f);
    __half2 z = __hmul2(a, __hfma2(c2, a2, c1));
    __half2 e = h2exp(z);
    const __half2 one = __float2half2_rn(1.0f);
    return __hmul2(a, h2rcp(__hadd2(one, e)));
}

__device__ __forceinline__ h4 gelu4(fx4 h) {
    union { __half2 p[2]; h4 v; } u;
    u.p[0] = gelu2(h[0], h[1]);
    u.p[1] = gelu2(h[2], h[3]);
    return u.v;
}

__device__ __forceinline__ float2 cmul(float2 a, float2 b) {
    return make_float2(a.x * b.x - a.y * b.y, a.x * b.y + a.y * b.x);
}

// exact magic divisor: umulhi(n, M) == n/d for n*d < 2^32, d >= 2
__device__ __forceinline__ unsigned magic_div(unsigned d) {
    return (unsigned)((0x100000000ULL + d - 1) / d);
}

// ---------------------------------------------------------------------------
// Inline top-2 of amp (4 KB) + period/weight derivation, per block.
// ---------------------------------------------------------------------------
__device__ __forceinline__ void compute_meta(const float* __restrict__ amp,
                                             float* sf, int* si, int tid,
                                             int& P1, int& cols1, int& P2, int& cols2,
                                             float& wg1, float& wg2) {
    float* v1s = sf;        float* v2s = sf + 256;
    int*   i1s = si;        int*   i2s = si + 256;
    float4 v4 = ((const float4*)amp)[tid];
    float vv[4] = {v4.x, v4.y, v4.z, v4.w};
    float v1 = -1e30f, v2 = -1e30f; int i1 = 1 << 30, i2 = 1 << 30;
    #pragma unroll
    for (int u = 0; u < 4; ++u) {
        int j = tid * 4 + u;
        float v = vv[u];
        if (v > v1) { v2 = v1; i2 = i1; v1 = v; i1 = j; }
        else if (v > v2) { v2 = v; i2 = j; }
    }
    v1s[tid] = v1; i1s[tid] = i1; v2s[tid] = v2; i2s[tid] = i2;
    __syncthreads();
    for (int st = 128; st > 0; st >>= 1) {
        if (tid < st) {
            float w1 = v1s[tid + st]; int j1 = i1s[tid + st];
            float w2 = v2s[tid + st]; int j2 = i2s[tid + st];
            float a1 = v1s[tid];      int a1i = i1s[tid];
            float a2 = v2s[tid];      int a2i = i2s[tid];
            float n1, n2; int n1i, n2i;
            bool w1_first = (w1 > a1) || (w1 == a1 && j1 < a1i);
            if (w1_first) {
                n1 = w1; n1i = j1;
                bool a1_next = (a1 > w2) || (a1 == w2 && a1i < j2);
                if (a1_next) { n2 = a1; n2i = a1i; } else { n2 = w2; n2i = j2; }
            } else {
                n1 = a1; n1i = a1i;
                bool w1_next = (w1 > a2) || (w1 == a2 && j1 < a2i);
                if (w1_next) { n2 = w1; n2i = j1; } else { n2 = a2; n2i = a2i; }
            }
            v1s[tid] = n1; i1s[tid] = n1i; v2s[tid] = n2; i2s[tid] = n2i;
        }
        __syncthreads();
    }
    float v1f = v1s[0], v2f = v2s[0];
    int f1 = i1s[0] + 1, f2 = i2s[0] + 1;
    __syncthreads();                 // scratch free for reuse after this
    P1 = (int)llround(2048.0 / (double)f1); if (P1 < 1) P1 = 1;
    P2 = (int)llround(2048.0 / (double)f2); if (P2 < 1) P2 = 1;
    cols1 = (T_LEN + P1 - 1) / P1;
    cols2 = (T_LEN + P2 - 1) / P2;
    float mx = fmaxf(v1f, v2f);
    float e1 = __expf(v1f - mx), e2 = __expf(v2f - mx);
    float inv = 1.0f / (e1 + e2);
    wg1 = e1 * inv; wg2 = e2 * inv;
}

// ---------------------------------------------------------------------------
// Kernel 1: one batch per block. 2048-pt real FFT via 1024-pt complex FFT of
// z[n] = x[2n] + i*x[2n+1] (radix-2^2 Stockham, 5 fused double stages, all
// 256 threads active every stage) + spectrum untangle. Also zeroes `out`
// (256 blocks x 180 float4 = exactly NB*HORIZON/4) for head_gemm's split-K.
// ---------------------------------------------------------------------------
__global__ __launch_bounds__(256) void fft_amp_kernel(const float* __restrict__ x,
                                                      float* __restrict__ amp,
                                                      float* __restrict__ out) {
    __shared__ float2 buf0[1024];
    __shared__ float2 buf1[1024];
    __shared__ float2 tw[512];
    const int tid = threadIdx.x;
    const int b = blockIdx.x;          // one batch per block

    // zero out slice for split-K accumulation (written 2 dispatches later)
    if (tid < 180) {
        const int zi = b * 180 + tid;   // 256*180 = 46080 = NB*HORIZON/4 exactly
        ((float4*)out)[zi] = make_float4(0.f, 0.f, 0.f, 0.f);
    }

    {
        float s, c;
        __sincosf((float)tid * 6.135923151542565e-3f, &s, &c);          // 2*pi/1024
        tw[tid] = make_float2(c, -s);
        __sincosf((float)(tid + 256) * 6.135923151542565e-3f, &s, &c);
        tw[tid + 256] = make_float2(c, -s);
    }
    // z[n] = x[2n] + i*x[2n+1] : float2 loads are exactly (even, odd) pairs
    const float2* xz = (const float2*)(x + b * T_LEN);
    buf0[tid]       = xz[tid];
    buf0[tid + 256] = xz[tid + 256];
    buf0[tid + 512] = xz[tid + 512];
    buf0[tid + 768] = xz[tid + 768];
    __syncthreads();

    float2* src = buf0;
    float2* dst = buf1;
    // 5 fused double stages: s = 0,2,4,6,8  (4^5 = 1024, natural order out)
    for (int s = 0; s < 10; s += 2) {
        const int Ns = 1 << s;
        const int j1 = tid;                 // 0..255, all active
        const int q  = j1 & (Ns - 1);
        const int hi = j1 >> s;
        float2 A = src[j1];
        float2 B = src[j1 + 512];
        float2 C = src[j1 + 256];
        float2 D = src[j1 + 768];
        float2 w  = tw[q << (9 - s)];
        float2 wB = cmul(w, B);
        float2 wD = cmul(w, D);
        float2 P0 = make_float2(A.x + wB.x, A.y + wB.y);
        float2 P1 = make_float2(A.x - wB.x, A.y - wB.y);
        float2 Q0 = make_float2(C.x + wD.x, C.y + wD.y);
        float2 Q1 = make_float2(C.x - wD.x, C.y - wD.y);
        float2 wa = tw[q << (8 - s)];
        float2 wb = tw[(q + Ns) << (8 - s)];
        float2 t0 = cmul(wa, Q0);
        float2 t1 = cmul(wb, Q1);
        const int O = (hi << (s + 2)) + q;
        dst[O]          = make_float2(P0.x + t0.x, P0.y + t0.y);
        dst[O + 2 * Ns] = make_float2(P0.x - t0.x, P0.y - t0.y);
        dst[O + Ns]     = make_float2(P1.x + t1.x, P1.y + t1.y);
        dst[O + 3 * Ns] = make_float2(P1.x - t1.x, P1.y - t1.y);
        __syncthreads();
        float2* tmp = src; src = dst; dst = tmp;
    }
    // src = Z[0..1023] natural order. Untangle to rfft bins k = kk+1 in 1..1024:
    //   A = (Z[k]+conj(Z[N-k]))/2, B = (Z[k]-conj(Z[N-k]))/(2i),
    //   X[k] = A + e^{-2pi i k/2048} * B ;  X[1024] = Re Z[0] - Im Z[0].
    const int rot = (b * 8) & 1023;
    #pragma unroll
    for (int j = 0; j < 4; ++j) {
        const int kk = (tid + j * 256 + rot) & 1023;
        const int k  = kk + 1;
        float mag;
        if (k == 1024) {
            float2 Z0 = src[0];
            mag = fabsf(Z0.x - Z0.y) * (1.0f / 256.0f);
        } else {
            float2 Zk = src[k];
            float2 Zn = src[1024 - k];
            float Ax = 0.5f * (Zk.x + Zn.x), Ay = 0.5f * (Zk.y - Zn.y);
            float Bx = 0.5f * (Zk.y + Zn.y), By = -0.5f * (Zk.x - Zn.x);
            float sn, cs;
            __sincosf((float)k * 3.0679615757712823e-3f, &sn, &cs);  // pi/1024
            float Xx = Ax + cs * Bx + sn * By;   // cmul((cs,-sn),(Bx,By)).x
            float Xy = Ay + cs * By - sn * Bx;   // cmul((cs,-sn),(Bx,By)).y
            mag = sqrtf(Xx * Xx + Xy * Xy) * (1.0f / 256.0f);
        }
        atomicAdd(amp + kk, mag);
    }
}

// ---------------------------------------------------------------------------
// Kernel 2 (fused): MFMA tap-sum conv fast path + tile fallback in ONE kernel.
// __launch_bounds__(256,4) caps VGPR at 128 -- R9 measured 48 VGPR for this
// exact fusion (the R4 explosion does not recur under launch_bounds), so the
// hot path keeps its occupancy. Saves one dispatch + one serial gap vs R8.
// Both paths' bodies are byte-identical to R8's verified kernels.
// ---------------------------------------------------------------------------
__global__ __launch_bounds__(256, 4) void conv_all_kernel(
    const float* __restrict__ x,
    const float* __restrict__ w1, const float* __restrict__ b1,
    const float* __restrict__ w2, const float* __restrict__ b2,
    const float* __restrict__ amp,
    float* __restrict__ ws)
{
    __shared__ __align__(16) unsigned char smem[SMEM_BYTES];
    const int tid = threadIdx.x;

    _Float16 (*dk)[HSTRIDE] = (_Float16 (*)[HSTRIDE])smem;
    _Float16* xs2 = (_Float16*)(smem + 25424);

    const int per = blockIdx.y;
    const int u   = blockIdx.x;        // 0..511
    const int b   = u >> 1;
    const int ci  = u & 1;
    const int t0  = ci * CHUNK;
    const int bT  = b * T_LEN;

    // stage x window early (P-independent); HBM latency hides under meta
    for (int j = tid; j < XS2N; j += 256) {
        const int t = t0 - 384 + j;
        xs2[j] = (_Float16)((j < 1792 && t >= 0 && t < T_LEN) ? x[bT + t] : 0.f);
    }

    int P1_, cols1, P2_, cols2; float wg1, wg2;
    compute_meta(amp, (float*)dk, (int*)dk + 512, tid, P1_, cols1, P2_, cols2, wg1, wg2);

    const int P    = per == 0 ? P1_ : P2_;
    const int cols = per == 0 ? cols1 : cols2;
    const float wgt = per == 0 ? wg1 : wg2;
    float* yout = ws + (per == 0 ? WS_Y0 : WS_Y1);

    if (P >= 2 && P <= PMAX_FAST) {
        // ================= fast path (R8-verified) =================
        const int U0  = t0 - (P + 1);
        const int HN  = CHUNK + 2 * P + 2;
        const unsigned MP = magic_div((unsigned)P);
        const int IB0 = 383 - P;

        const int lane = tid & 63;
        const int wv   = tid >> 6;
        const int lm   = lane & 15;
        const int lg   = lane >> 4;

        h4  w1f[4], w2f[4];
        fx4 b1f[4];
        #pragma unroll
        for (int t = 0; t < 4; ++t) {
            #pragma unroll
            for (int i = 0; i < 4; ++i) {
                const int k = lg * 4 + i;
                w1f[t][i] = (_Float16)((k < 9) ? w1[(t * 16 + lm) * 9 + k] : 0.f);
                w2f[t][i] = (_Float16)((lm < 9) ? w2[(t * 16 + k) * 9 + lm] : 0.f);
                b1f[t][i] = b1[t * 16 + k];
            }
        }

        const int HN16 = (HN + 15) >> 4;
        const fx4 zf4 = {0.f, 0.f, 0.f, 0.f};

        for (int nt = wv; nt < HN16; nt += 4) {
            const int ih = nt * 16 + lm;
            const int uu0 = U0 + ih;
            const int uu = uu0 < 0 ? 0 : uu0;
            const int cc = (int)__umulhi((unsigned)uu, MP);
            const int pp = uu - cc * P;
            const bool rm = pp > 0, rp = pp < P - 1, cm = cc > 0, cp = (cc + 1) < cols;
            const int ibase = ih + IB0;
            h4 xb;
            #pragma unroll
            for (int j = 0; j < 4; ++j) {
                const int tap = lg * 4 + j;
                const int q = (tap * 86) >> 8;    // tap/3 (exact for tap<12)
                const int r = tap - q * 3;
                const bool ok = (tap < 9)
                    && (q > 0 || rm) && (q < 2 || rp)
                    && (r > 0 || cm) && (r < 2 || cp);
                const int addr = ok ? (ibase + (r - 1) * P + (q - 1)) : ZXS;
                xb[j] = xs2[addr];
            }
            fx4 h0 = __builtin_amdgcn_mfma_f32_16x16x16f16(w1f[0], xb, b1f[0], 0, 0, 0);
            fx4 h1 = __builtin_amdgcn_mfma_f32_16x16x16f16(w1f[1], xb, b1f[1], 0, 0, 0);
            fx4 h2 = __builtin_amdgcn_mfma_f32_16x16x16f16(w1f[2], xb, b1f[2], 0, 0, 0);
            fx4 h3 = __builtin_amdgcn_mfma_f32_16x16x16f16(w1f[3], xb, b1f[3], 0, 0, 0);
            h4 g0 = gelu4(h0);
            h4 g1 = gelu4(h1);
            h4 g2 = gelu4(h2);
            h4 g3 = gelu4(h3);
            fx4 da = __builtin_amdgcn_mfma_f32_16x16x16f16(w2f[0], g0, zf4, 0, 0, 0);
            fx4 db = __builtin_amdgcn_mfma_f32_16x16x16f16(w2f[1], g1, zf4, 0, 0, 0);
            da = __builtin_amdgcn_mfma_f32_16x16x16f16(w2f[2], g2, da, 0, 0, 0);
            db = __builtin_amdgcn_mfma_f32_16x16x16f16(w2f[3], g3, db, 0, 0, 0);
            if (ih < HN) {
                #pragma unroll
                for (int i = 0; i < 4; ++i) {
                    const int row = lg * 4 + i;
                    if (row < 9) dk[row][ih] = (_Float16)(da[i] + db[i]);
                }
            }
        }
        if (tid < 9) dk[tid][ZSLOT] = (_Float16)0.f;
        __syncthreads();

        const float bias2 = b2[0];
        #pragma unroll
        for (int o = 0; o < 4; ++o) {
            const int t = t0 + tid + o * 256;
            const int iout = tid + o * 256 + (P + 1);
            const int cc = (int)__umulhi((unsigned)t, MP);
            const int pp = t - cc * P;
            const bool rm = pp > 0, rp = pp < P - 1, cm = cc > 0, cp = (cc + 1) < cols;
            const int i0 = (rm && cm) ? iout - P - 1 : ZSLOT;
            const int i1 = rm         ? iout - 1     : ZSLOT;
            const int i2 = (rm && cp) ? iout + P - 1 : ZSLOT;
            const int i3 = cm         ? iout - P     : ZSLOT;
            const int i5 = cp         ? iout + P     : ZSLOT;
            const int i6 = (rp && cm) ? iout - P + 1 : ZSLOT;
            const int i7 = rp         ? iout + 1     : ZSLOT;
            const int i8 = (rp && cp) ? iout + P + 1 : ZSLOT;
            float s = (float)dk[4][iout];
            s += (float)dk[0][i0]; s += (float)dk[1][i1]; s += (float)dk[2][i2];
            s += (float)dk[3][i3]; s += (float)dk[5][i5]; s += (float)dk[6][i6];
            s += (float)dk[7][i7]; s += (float)dk[8][i8];
            yout[bT + t] = wgt * (s + bias2);
        }
    } else {
        // ================= fallback tile path (rare) =================
        float* w1s = (float*)smem;                       // [576]
        float* w2s = w1s + 576;                          // [576]
        float* b1s = w2s + 576;                          // [64]
        float (*fxs)[13] = (float (*)[13])(b1s + 64);    // [12][13]
        float (*hs)[101] = (float (*)[101])(b1s + 64 + 156); // [64][101]

        for (int i = tid; i < DMODEL * 9; i += 256) { w1s[i] = w1[i]; w2s[i] = w2[i]; }
        if (tid < DMODEL) b1s[tid] = b1[tid];
        const float bias2 = b2[0];

        const int tp = (P + 7) >> 3;
        const int tc = (cols + 7) >> 3;
        const int tiles_img = tp * tc;
        const int total = tiles_img * NB;

        for (int tile = u; tile < total; tile += 512) {
            const int bb = tile / tiles_img;
            const int ti  = tile - bb * tiles_img;
            const int tpi = ti / tc;
            const int tci = ti - tpi * tc;
            const int p0 = tpi * 8, c0 = tci * 8;

            __syncthreads();
            if (tid < 144) {
                int i = tid / 12, j = tid - (tid / 12) * 12;
                int pp = p0 - 2 + i, cc = c0 - 2 + j;
                float v = 0.f;
                if (pp >= 0 && pp < P && cc >= 0 && cc < cols) {
                    int t = cc * P + pp;
                    if (t < T_LEN) v = x[bb * T_LEN + t];
                }
                fxs[i][j] = v;
            }
            __syncthreads();

            for (int it = 0; it < 25; ++it) {
                int idx = it * 256 + tid;
                int ch = idx / 100;
                int px = idx - ch * 100;
                int pi = px / 10;
                int pj = px - pi * 10;
                const float* w = &w1s[ch * 9];
                float a = b1s[ch];
                a = fmaf(w[0], fxs[pi    ][pj    ], a);
                a = fmaf(w[1], fxs[pi    ][pj + 1], a);
                a = fmaf(w[2], fxs[pi    ][pj + 2], a);
                a = fmaf(w[3], fxs[pi + 1][pj    ], a);
                a = fmaf(w[4], fxs[pi + 1][pj + 1], a);
                a = fmaf(w[5], fxs[pi + 1][pj + 2], a);
                a = fmaf(w[6], fxs[pi + 2][pj    ], a);
                a = fmaf(w[7], fxs[pi + 2][pj + 1], a);
                a = fmaf(w[8], fxs[pi + 2][pj + 2], a);
                float g = gelu_fast(a);
                int pp = p0 - 1 + pi, cc = c0 - 1 + pj;
                bool in_img = (pp >= 0) & (pp < P) & (cc >= 0) & (cc < cols);
                hs[ch][px] = in_img ? g : 0.0f;
            }
            __syncthreads();

            {
                const int pixel = tid >> 2, part = tid & 3;
                const int pi = pixel >> 3, pj = pixel & 7;
                const int base = pi * 10 + pj;
                float s = 0.f;
                for (int ch = part * 16; ch < part * 16 + 16; ++ch) {
                    const float* w  = &w2s[ch * 9];
                    const float* hr = &hs[ch][base];
                    s = fmaf(w[0], hr[0],  s);
                    s = fmaf(w[1], hr[1],  s);
                    s = fmaf(w[2], hr[2],  s);
                    s = fmaf(w[3], hr[10], s);
                    s = fmaf(w[4], hr[11], s);
                    s = fmaf(w[5], hr[12], s);
                    s = fmaf(w[6], hr[20], s);
                    s = fmaf(w[7], hr[21], s);
                    s = fmaf(w[8], hr[22], s);
                }
                s += __shfl_down(s, 1);
                s += __shfl_down(s, 2);
                if (part == 0) {
                    int pp = p0 + pi, cc = c0 + pj;
                    if (pp < P && cc < cols) {
                        int t = cc * P + pp;
                        if (t < T_LEN) yout[bb * T_LEN + t] = wgt * (s + bias2);
                    }
                }
            }
        }
    }
}

// ---------------------------------------------------------------------------
// Kernel 3: MFMA head GEMM, split-K x8. 32x32 tile per block, 4 waves = 4
// 16x16 quadrants; K-chunk 256 staged as 64-wide f16 LDS tiles. grid
// (8, 23, 8) = 1472 blocks (~5.7/CU). Partials atomicAdd'ed into out
// (zeroed by fft_amp); z==0 adds bias.
// ---------------------------------------------------------------------------
#define HG_KC 256
__global__ __launch_bounds__(256) void head_gemm_kernel(
    const float* __restrict__ ws, const float* __restrict__ hw,
    const float* __restrict__ hb, float* __restrict__ out)
{
    __shared__ _Float16 As[32][72];   // [m][k], row pad 72 f16 = 144 B
    __shared__ _Float16 Bs[32][72];   // [n][k]
    const float* y0 = ws + WS_Y0;
    const float* y1 = ws + WS_Y1;
    const int tid = threadIdx.x;
    const int b0 = blockIdx.x * 32, h0 = blockIdx.y * 32;
    const int kc0 = blockIdx.z * HG_KC;
    const int lane = tid & 63;
    const int wv   = tid >> 6;
    const int lm   = lane & 15;
    const int lg   = lane >> 4;
    const int wm   = (wv & 1) * 16;    // wave's row quadrant
    const int wn   = (wv >> 1) * 16;   // wave's col quadrant
    const int sr = tid >> 4;           // 0..15
    const int sq = (tid & 15) * 4;     // 0,4,...,60

    fx4 acc = {0.f, 0.f, 0.f, 0.f};

    for (int k0 = kc0; k0 < kc0 + HG_KC; k0 += 64) {
        #pragma unroll
        for (int hh = 0; hh < 2; ++hh) {
            const int r = sr + hh * 16;
            const int src = (b0 + r) * T_LEN + k0 + sq;
            float4 u = *(const float4*)(y0 + src);
            float4 v = *(const float4*)(y1 + src);
            As[r][sq + 0] = (_Float16)(u.x + v.x);
            As[r][sq + 1] = (_Float16)(u.y + v.y);
            As[r][sq + 2] = (_Float16)(u.z + v.z);
            As[r][sq + 3] = (_Float16)(u.w + v.w);
            const int hr = h0 + r;
            float4 w = (hr < HORIZON) ? *(const float4*)(hw + hr * T_LEN + k0 + sq)
                                      : make_float4(0.f, 0.f, 0.f, 0.f);
            Bs[r][sq + 0] = (_Float16)w.x;
            Bs[r][sq + 1] = (_Float16)w.y;
            Bs[r][sq + 2] = (_Float16)w.z;
            Bs[r][sq + 3] = (_Float16)w.w;
        }
        __syncthreads();
        #pragma unroll
        for (int kk = 0; kk < 64; kk += 16) {
            h4 af = *(const h4*)&As[wm + lm][kk + lg * 4];
            h4 bf = *(const h4*)&Bs[wn + lm][kk + lg * 4];
            acc = __builtin_amdgcn_mfma_f32_16x16x16f16(af, bf, acc, 0, 0, 0);
        }
        __syncthreads();
    }
    // D layout: col = lane&15, row = 4*(lane>>4)+i  (row follows A's m)
    const int ncol = h0 + wn + lm;
    if (ncol < HORIZON) {
        const float bb = (blockIdx.z == 0) ? hb[ncol] : 0.f;
        #pragma unroll
        for (int i = 0; i < 4; ++i) {
            const int m = b0 + wm + lg * 4 + i;
            atomicAdd(&out[m * HORIZON + ncol], acc[i] + bb);
        }
    }
}

// ---------------------------------------------------------------------------
extern "C" void kernel_launch(void* const* d_in, const int* in_sizes, int n_in,
                              void* d_out, int out_size, void* d_ws, size_t ws_size,
                              hipStream_t stream) {
    const float* x   = (const float*)d_in[0];
    const float* c1w = (const float*)d_in[1];
    const float* c1b = (const float*)d_in[2];
    const float* c2w = (const float*)d_in[3];
    const float* c2b = (const float*)d_in[4];
    const float* hw  = (const float*)d_in[5];
    const float* hb  = (const float*)d_in[6];
    float* out = (float*)d_out;
    float* ws  = (float*)d_ws;

    float* amp = ws + WS_AMP;

    hipMemsetAsync(amp, 0, N_FREQ * sizeof(float), stream);
    fft_amp_kernel<<<NB, 256, 0, stream>>>(x, amp, out);
    conv_all_kernel<<<dim3(512, 2), 256, 0, stream>>>(x, c1w, c1b, c2w, c2b, amp, ws);
    head_gemm_kernel<<<dim3(NB / 32, (HORIZON + 31) / 32, T_LEN / HG_KC), 256, 0, stream>>>(ws, hw, hb, out);
}